// Round 6
// baseline (382.405 us; speedup 1.0000x reference)
//
#include <hip/hip_runtime.h>

// MultiHeadTEAttention: M=8, NQ=NKV=1024, DX=512, H=8, HD=64, KHID=16, DT=2
// f32 in/out; bf16 MFMA compute.

typedef unsigned short u16;
typedef unsigned int   u32;
typedef short bf8 __attribute__((ext_vector_type(8)));   // 8 bf16 = 4 VGPR
typedef float f4  __attribute__((ext_vector_type(4)));

#define Mb 8
#define SCALE 0.125f

__device__ __forceinline__ u16 f2bf(float f) {
    union { float f; u32 u; } v; v.f = f;
    u32 r = v.u + 0x7fffu + ((v.u >> 16) & 1u);   // RNE
    return (u16)(r >> 16);
}
__device__ __forceinline__ u32 pk2(float a, float b) {
    return (u32)f2bf(a) | ((u32)f2bf(b) << 16);
}

// ===========================================================================
// xconv: xq,xk,xv f32 -> contiguous bf16 Xb[3][8192][512]. Pure BW kernel.
// ===========================================================================
__global__ __launch_bounds__(256) void xconv(
    const float* __restrict__ a, const float* __restrict__ b,
    const float* __restrict__ c, u16* __restrict__ o)
{
    const size_t n = (size_t)Mb * 1024 * 512;
    size_t i = ((size_t)blockIdx.x * 256 + threadIdx.x) * 8;
    const float* src; size_t off;
    if (i < n)          { src = a; off = i; }
    else if (i < 2 * n) { src = b; off = i - n; }
    else                { src = c; off = i - 2 * n; }
    float4 v0 = *(const float4*)(src + off);
    float4 v1 = *(const float4*)(src + off + 4);
    uint4 u;
    u.x = pk2(v0.x, v0.y); u.y = pk2(v0.z, v0.w);
    u.z = pk2(v1.x, v1.y); u.w = pk2(v1.z, v1.w);
    *(uint4*)(o + i) = u;
}

// ===========================================================================
// svpre: svg[m][k][c] f32 = tk[m][k][:] @ kw1[:,c]   (8192 x 16)
// ===========================================================================
__global__ __launch_bounds__(256) void svpre(
    const float* __restrict__ tk, const float* __restrict__ kw1,
    float* __restrict__ svg)
{
    const int t = blockIdx.x * 256 + threadIdx.x;   // (m,k) pair, 8192 total
    const float t0 = tk[(size_t)t * 2], t1 = tk[(size_t)t * 2 + 1];
    float* op = svg + (size_t)t * 16;
    #pragma unroll
    for (int cc = 0; cc < 4; ++cc) {
        float4 v;
        v.x = fmaf(t0, kw1[cc * 4 + 0], t1 * kw1[16 + cc * 4 + 0]);
        v.y = fmaf(t0, kw1[cc * 4 + 1], t1 * kw1[16 + cc * 4 + 1]);
        v.z = fmaf(t0, kw1[cc * 4 + 2], t1 * kw1[16 + cc * 4 + 2]);
        v.w = fmaf(t0, kw1[cc * 4 + 3], t1 * kw1[16 + cc * 4 + 3]);
        *(float4*)(op + cc * 4) = v;
    }
}

// ===========================================================================
// Weight transpose+convert: Wt[n][k] bf16 = W[k][n] f32. 512x512, 4 matrices.
// ===========================================================================
__global__ __launch_bounds__(256) void wconv(
    const float* __restrict__ w0, const float* __restrict__ w1,
    const float* __restrict__ w2, const float* __restrict__ w3,
    u16* __restrict__ o0, u16* __restrict__ o1,
    u16* __restrict__ o2, u16* __restrict__ o3)
{
    const float* W[4] = {w0, w1, w2, w3};
    u16*         O[4] = {o0, o1, o2, o3};
    __shared__ float L[64][65];
    const int z = blockIdx.z, tid = threadIdx.x;
    const int k0 = blockIdx.x * 64, n0 = blockIdx.y * 64;
    const float* Wz = W[z];
    #pragma unroll
    for (int i = 0; i < 16; ++i) {
        int idx = tid + i * 256;
        int k = idx >> 6, n = idx & 63;
        L[n][k] = Wz[(size_t)(k0 + k) * 512 + n0 + n];
    }
    __syncthreads();
    u32* Oz = (u32*)O[z];
    #pragma unroll
    for (int i = 0; i < 8; ++i) {
        int idx = tid + i * 256;
        int n = idx >> 5, kp = idx & 31;
        Oz[((size_t)(n0 + n) * 512 + k0 + kp * 2) >> 1] = pk2(L[n][kp * 2], L[n][kp * 2 + 1]);
    }
}

// ===========================================================================
// GEMM: C = A[8192x512](bf16) @ Wt^T (+bias). Wt bf16 [n][k].
// 128x128 tile, BK=32, LDS [seg(4)][row(128)][8 bf16]. Staging = pure copies.
// ===========================================================================
struct GArgs {
    const u16* A[3];
    const u16* W[3];
    void*      C[3];
    const float* bias;
    int modeT[3];
    int outf32;
};

__global__ __launch_bounds__(256) void gemm_mfma(GArgs g) {
    __shared__ u16 Xs[4][128][8];
    __shared__ u16 Ws[4][128][8];

    const int z   = blockIdx.z;
    const int tid = threadIdx.x;
    const int w = tid >> 6, lane = tid & 63, quad = lane >> 4, l16 = lane & 15;
    const int wm = w >> 1, wn = w & 1;
    const int n0 = blockIdx.x * 128, t0 = blockIdx.y * 128;
    const int trans = g.modeT[z];

    f4 acc[4][4];
    #pragma unroll
    for (int i = 0; i < 4; ++i)
        #pragma unroll
        for (int j = 0; j < 4; ++j) acc[i][j] = (f4)0.f;

    const u16* Ap = g.A[z];
    const u16* Wp = g.W[z];

    for (int kc = 0; kc < 512; kc += 32) {
        __syncthreads();
        #pragma unroll
        for (int i = 0; i < 2; ++i) {
            const int cc = tid + i * 256;
            const int row = cc >> 2, seg = cc & 3;
            *(uint4*)&Xs[seg][row][0] =
                *(const uint4*)(Ap + (size_t)(t0 + row) * 512 + kc + seg * 8);
            *(uint4*)&Ws[seg][row][0] =
                *(const uint4*)(Wp + (size_t)(n0 + row) * 512 + kc + seg * 8);
        }
        __syncthreads();

        const u16 (*Aop)[128][8] = trans ? Xs : Ws;
        const u16 (*Bop)[128][8] = trans ? Ws : Xs;
        const int arow = (trans ? wm : wn) * 64;
        const int brow = (trans ? wn : wm) * 64;
        bf8 af[4], bf[4];
        #pragma unroll
        for (int i = 0; i < 4; ++i) af[i] = *(const bf8*)&Aop[quad][arow + i * 16 + l16][0];
        #pragma unroll
        for (int j = 0; j < 4; ++j) bf[j] = *(const bf8*)&Bop[quad][brow + j * 16 + l16][0];
        #pragma unroll
        for (int i = 0; i < 4; ++i)
            #pragma unroll
            for (int j = 0; j < 4; ++j)
                acc[i][j] = __builtin_amdgcn_mfma_f32_16x16x32_bf16(af[i], bf[j], acc[i][j], 0, 0, 0);
    }

    if (g.outf32) {
        float* Co = (float*)g.C[z];
        #pragma unroll
        for (int i = 0; i < 4; ++i) {
            const int nb = n0 + wn * 64 + i * 16 + quad * 4;
            float4 bv = *(const float4*)&g.bias[nb];
            #pragma unroll
            for (int j = 0; j < 4; ++j) {
                const int tok = t0 + wm * 64 + j * 16 + l16;
                float4 st;
                st.x = acc[i][j][0] + bv.x; st.y = acc[i][j][1] + bv.y;
                st.z = acc[i][j][2] + bv.z; st.w = acc[i][j][3] + bv.w;
                *(float4*)&Co[(size_t)tok * 512 + nb] = st;
            }
        }
    } else if (!trans) {
        u16* C = (u16*)g.C[z];
        #pragma unroll
        for (int i = 0; i < 4; ++i) {
            const int nb = n0 + wn * 64 + i * 16 + quad * 4;
            #pragma unroll
            for (int j = 0; j < 4; ++j) {
                const int tok = t0 + wm * 64 + j * 16 + l16;
                uint2 pw;
                pw.x = pk2(acc[i][j][0], acc[i][j][1]);
                pw.y = pk2(acc[i][j][2], acc[i][j][3]);
                *(uint2*)&C[(size_t)tok * 512 + nb] = pw;
            }
        }
    } else {
        u16* Vt = (u16*)g.C[z];
        #pragma unroll
        for (int i = 0; i < 4; ++i) {
            const int tokb = t0 + wm * 64 + i * 16 + quad * 4;
            const int mb = tokb >> 10, tb = tokb & 1023;
            #pragma unroll
            for (int j = 0; j < 4; ++j) {
                const int n = n0 + wn * 64 + j * 16 + l16;
                uint2 pw;
                pw.x = pk2(acc[i][j][0], acc[i][j][1]);
                pw.y = pk2(acc[i][j][2], acc[i][j][3]);
                *(uint2*)&Vt[(size_t)mb * 524288 + (size_t)n * 1024 + tb] = pw;
            }
        }
    }
}

// ===========================================================================
// Fused attention v4: block = (m, 16-q tile), 512 threads = 8 waves = 8 heads.
// Grid 512 -> 2 blocks/CU. ONE barrier per k-tile (double-buffered sB).
// sB layout [k][q*9+h], k-stride 149 (odd, ==21 mod 32): <=2-way banks.
// ===========================================================================
__global__ __launch_bounds__(512) void attn_mfma(
    const u16* __restrict__ Q, const u16* __restrict__ K,
    const u16* __restrict__ Vt,
    const float* __restrict__ tqp, const float* __restrict__ svg,
    const float* __restrict__ kw1, const float* __restrict__ kb1,
    const float* __restrict__ kw2,
    u16* __restrict__ O)
{
    __shared__ float sB[2][32][149];   // [p][k][q*9 + h]
    __shared__ u16   sP[8][16][40];    // per-wave P [q][k]

    const int tid = threadIdx.x;
    const int w = tid >> 6, lane = tid & 63, quad = lane >> 4, l16 = lane & 15;
    const int m = blockIdx.x;          // blockIdx.x = m -> XCD ~ m (L2 locality)
    const int q0 = blockIdx.y * 16;
    const int h = w;

    // Q fragments
    bf8 qf[2];
    #pragma unroll
    for (int kc = 0; kc < 2; ++kc)
        qf[kc] = *(const bf8*)(Q + ((size_t)m * 1024 + q0 + l16) * 512
                                 + h * 64 + kc * 32 + quad * 8);
    // u[j]: c = (quad&1)*8 + j  (phase-B A-frag c-coverage for quads 0,1)
    float u8[8];
    {
        const size_t qi = ((size_t)m * 1024 + q0 + l16) * 2;
        const float t0v = tqp[qi], t1v = tqp[qi + 1];
        #pragma unroll
        for (int j = 0; j < 8; ++j) {
            const int c = (quad & 1) * 8 + j;
            u8[j] = fmaf(t0v, kw1[c], fmaf(t1v, kw1[16 + c], kb1[c]));
        }
    }
    // kw2 B-fragment (n = l16 = h for l16<8; k-dim c = quad*8+j, zero for c>=16)
    bf8 b2;
    {
        union { uint4 u4; bf8 v; } cv; cv.u4 = make_uint4(0, 0, 0, 0);
        if (l16 < 8 && quad < 2) {
            u32 r[4];
            #pragma unroll
            for (int pp = 0; pp < 4; ++pp) {
                const int c = quad * 8 + pp * 2;
                r[pp] = pk2(kw2[c * 8 + l16], kw2[(c + 1) * 8 + l16]);
            }
            cv.u4 = make_uint4(r[0], r[1], r[2], r[3]);
        }
        b2 = cv.v;
    }

    float mrun = -1e30f, lrun = 0.f;
    f4 o[4];
    #pragma unroll
    for (int d = 0; d < 4; ++d) o[d] = (f4)0.f;

    int p = 0;
    for (int kt = 0; kt < 32; ++kt) {
        const int k0 = kt * 32;

        // ---- global loads (consumed after barrier; latency hidden) ----
        bf8 kf[2][2], vf[4];
        #pragma unroll
        for (int ms = 0; ms < 2; ++ms)
            #pragma unroll
            for (int kc = 0; kc < 2; ++kc)
                kf[ms][kc] = *(const bf8*)(K + ((size_t)m * 1024 + k0 + ms * 16 + l16) * 512
                                             + h * 64 + kc * 32 + quad * 8);
        #pragma unroll
        for (int ds = 0; ds < 4; ++ds)
            vf[ds] = *(const bf8*)(Vt + (size_t)m * 524288
                                      + (size_t)(h * 64 + ds * 16 + l16) * 1024 + k0 + quad * 8);
        float4 vb[4][2];
        if (quad < 2) {
            #pragma unroll
            for (int tl = 0; tl < 4; ++tl) {
                const float* vp = svg + ((size_t)m * 1024 + k0 + w * 4 + tl) * 16 + quad * 8;
                vb[tl][0] = *(const float4*)vp;
                vb[tl][1] = *(const float4*)(vp + 4);
            }
        }

        // ---- phase B: bias MFMA for k-rows 4w..4w+3, all heads ----
        #pragma unroll
        for (int tl = 0; tl < 4; ++tl) {
            union { uint4 u4; bf8 v; } cv; cv.u4 = make_uint4(0, 0, 0, 0);
            if (quad < 2) {
                cv.u4.x = pk2(fmaxf(u8[0] - vb[tl][0].x, 0.f), fmaxf(u8[1] - vb[tl][0].y, 0.f));
                cv.u4.y = pk2(fmaxf(u8[2] - vb[tl][0].z, 0.f), fmaxf(u8[3] - vb[tl][0].w, 0.f));
                cv.u4.z = pk2(fmaxf(u8[4] - vb[tl][1].x, 0.f), fmaxf(u8[5] - vb[tl][1].y, 0.f));
                cv.u4.w = pk2(fmaxf(u8[6] - vb[tl][1].z, 0.f), fmaxf(u8[7] - vb[tl][1].w, 0.f));
            }
            f4 d = __builtin_amdgcn_mfma_f32_16x16x32_bf16(cv.v, b2, (f4)0.f, 0, 0, 0);
            // D: row(quad*4+r) = q, col(l16) = h
            if (l16 < 8) {
                #pragma unroll
                for (int r = 0; r < 4; ++r)
                    sB[p][w * 4 + tl][(quad * 4 + r) * 9 + l16] = d[r];
            }
        }
        __syncthreads();   // sB[p] ready; prev phase C (reads of sB[p^1]) done

        // ---- phase C: S^T, softmax, P·V ----
        f4 s[2];
        #pragma unroll
        for (int ms = 0; ms < 2; ++ms) {
            s[ms] = __builtin_amdgcn_mfma_f32_16x16x32_bf16(kf[ms][0], qf[0], (f4)0.f, 0, 0, 0);
            s[ms] = __builtin_amdgcn_mfma_f32_16x16x32_bf16(kf[ms][1], qf[1], s[ms], 0, 0, 0);
        }
        #pragma unroll
        for (int ms = 0; ms < 2; ++ms)
            #pragma unroll
            for (int r = 0; r < 4; ++r)
                s[ms][r] = fmaf(s[ms][r], SCALE,
                                sB[p][ms * 16 + quad * 4 + r][l16 * 9 + h]);

        float mx = fmaxf(fmaxf(fmaxf(s[0][0], s[0][1]), fmaxf(s[0][2], s[0][3])),
                         fmaxf(fmaxf(s[1][0], s[1][1]), fmaxf(s[1][2], s[1][3])));
        mx = fmaxf(mx, __shfl_xor(mx, 16));
        mx = fmaxf(mx, __shfl_xor(mx, 32));
        const float mnew = fmaxf(mrun, mx);
        const float alpha = __expf(mrun - mnew);
        float ps = 0.f;
        #pragma unroll
        for (int ms = 0; ms < 2; ++ms)
            #pragma unroll
            for (int r = 0; r < 4; ++r) {
                float pv = __expf(s[ms][r] - mnew);
                s[ms][r] = pv;
                ps += pv;
            }
        ps += __shfl_xor(ps, 16);
        ps += __shfl_xor(ps, 32);
        lrun = lrun * alpha + ps;
        mrun = mnew;
        #pragma unroll
        for (int ds = 0; ds < 4; ++ds) o[ds] = o[ds] * alpha;

        #pragma unroll
        for (int ms = 0; ms < 2; ++ms) {
            uint2 pw;
            pw.x = pk2(s[ms][0], s[ms][1]);
            pw.y = pk2(s[ms][2], s[ms][3]);
            *(uint2*)&sP[w][l16][ms * 16 + quad * 4] = pw;
        }
        bf8 pf = *(const bf8*)&sP[w][l16][quad * 8];
        #pragma unroll
        for (int ds = 0; ds < 4; ++ds)
            o[ds] = __builtin_amdgcn_mfma_f32_16x16x32_bf16(vf[ds], pf, o[ds], 0, 0, 0);

        p ^= 1;
    }

    // ---- epilogue ----
    const float inv = 1.f / lrun;
    u16* og = O + ((size_t)m * 1024 + q0 + l16) * 512 + h * 64;
    #pragma unroll
    for (int ds = 0; ds < 4; ++ds) {
        uint2 pw;
        pw.x = pk2(o[ds][0] * inv, o[ds][1] * inv);
        pw.y = pk2(o[ds][2] * inv, o[ds][3] * inv);
        *(uint2*)(og + ds * 16 + quad * 4) = pw;
    }
}

// ===========================================================================
extern "C" void kernel_launch(void* const* d_in, const int* in_sizes, int n_in,
                              void* d_out, int out_size, void* d_ws, size_t ws_size,
                              hipStream_t stream) {
    const float* xq    = (const float*)d_in[0];
    const float* xk    = (const float*)d_in[1];
    const float* xv    = (const float*)d_in[2];
    const float* tq    = (const float*)d_in[3];
    const float* tk    = (const float*)d_in[4];
    const float* w_q   = (const float*)d_in[5];
    const float* w_k   = (const float*)d_in[6];
    const float* w_v   = (const float*)d_in[7];
    const float* w_out = (const float*)d_in[8];
    const float* b_out = (const float*)d_in[9];
    const float* kw1   = (const float*)d_in[10];
    const float* kb1   = (const float*)d_in[11];
    const float* kw2   = (const float*)d_in[12];

    const size_t nTok = (size_t)Mb * 1024 * 512;   // 4,194,304
    u16* Qw  = (u16*)d_ws;
    u16* Kp  = Qw + nTok;
    u16* Vt  = Kp + nTok;
    u16* Ob  = Vt + nTok;
    u16* Wt0 = Ob + nTok;           // w_q^T
    u16* Wt1 = Wt0 + 512 * 512;
    u16* Wt2 = Wt1 + 512 * 512;
    u16* Wt3 = Wt2 + 512 * 512;     // w_out^T
    u16* Xb  = Wt3 + 512 * 512;     // bf16 xq,xk,xv [3][8192][512]
    float* svg = (float*)(Xb + 3 * nTok);   // [8][1024][16]

    xconv<<<6144, 256, 0, stream>>>(xq, xk, xv, Xb);
    wconv<<<dim3(8, 8, 4), 256, 0, stream>>>(w_q, w_k, w_v, w_out, Wt0, Wt1, Wt2, Wt3);
    svpre<<<32, 256, 0, stream>>>(tk, kw1, svg);

    GArgs gq;
    gq.A[0] = Xb; gq.A[1] = Xb + nTok; gq.A[2] = Xb + 2 * nTok;
    gq.W[0] = Wt0; gq.W[1] = Wt1; gq.W[2] = Wt2;
    gq.C[0] = Qw;  gq.C[1] = Kp;  gq.C[2] = Vt;
    gq.bias = nullptr;
    gq.modeT[0] = 0; gq.modeT[1] = 0; gq.modeT[2] = 1;
    gq.outf32 = 0;
    gemm_mfma<<<dim3(4, 64, 3), 256, 0, stream>>>(gq);

    attn_mfma<<<dim3(8, 64), 512, 0, stream>>>(Qw, Kp, Vt, tq, svg,
                                               kw1, kb1, kw2, Ob);

    GArgs go;
    go.A[0] = Ob;  go.A[1] = Ob;  go.A[2] = Ob;
    go.W[0] = Wt3; go.W[1] = Wt3; go.W[2] = Wt3;
    go.C[0] = d_out; go.C[1] = d_out; go.C[2] = d_out;
    go.bias = b_out;
    go.modeT[0] = 0; go.modeT[1] = 0; go.modeT[2] = 0;
    go.outf32 = 1;
    gemm_mfma<<<dim3(4, 64, 1), 256, 0, stream>>>(go);
}

// Round 7
// 362.618 us; speedup vs baseline: 1.0546x; 1.0546x over previous
//
#include <hip/hip_runtime.h>

// MultiHeadTEAttention: M=8, NQ=NKV=1024, DX=512, H=8, HD=64, KHID=16, DT=2
// f32 in/out; bf16 MFMA compute. Bias MLP via 32x32x16 MFMA (K=16=KHID).

typedef unsigned short u16;
typedef unsigned int   u32;
typedef short bf8  __attribute__((ext_vector_type(8)));    // 8 bf16 = 4 VGPR
typedef float f4   __attribute__((ext_vector_type(4)));
typedef float f16v __attribute__((ext_vector_type(16)));

#define Mb 8
#define SCALE 0.125f

__device__ __forceinline__ u16 f2bf(float f) {
    union { float f; u32 u; } v; v.f = f;
    u32 r = v.u + 0x7fffu + ((v.u >> 16) & 1u);   // RNE
    return (u16)(r >> 16);
}
__device__ __forceinline__ u32 pk2(float a, float b) {
    return (u32)f2bf(a) | ((u32)f2bf(b) << 16);
}
__device__ __forceinline__ float b2f(u16 v) {
    union { u32 u; float f; } c; c.u = ((u32)v) << 16; return c.f;
}

// ===========================================================================
// xconv: xq,xk,xv f32 -> contiguous bf16 Xb[3][8192][512].
// ===========================================================================
__global__ __launch_bounds__(256) void xconv(
    const float* __restrict__ a, const float* __restrict__ b,
    const float* __restrict__ c, u16* __restrict__ o)
{
    const size_t n = (size_t)Mb * 1024 * 512;
    size_t i = ((size_t)blockIdx.x * 256 + threadIdx.x) * 8;
    const float* src; size_t off;
    if (i < n)          { src = a; off = i; }
    else if (i < 2 * n) { src = b; off = i - n; }
    else                { src = c; off = i - 2 * n; }
    float4 v0 = *(const float4*)(src + off);
    float4 v1 = *(const float4*)(src + off + 4);
    uint4 u;
    u.x = pk2(v0.x, v0.y); u.y = pk2(v0.z, v0.w);
    u.z = pk2(v1.x, v1.y); u.w = pk2(v1.z, v1.w);
    *(uint4*)(o + i) = u;
}

// ===========================================================================
// svpre: svg[m][k][c] f32 = tk[m][k][:] @ kw1[:,c]   (8192 x 16)
// ===========================================================================
__global__ __launch_bounds__(256) void svpre(
    const float* __restrict__ tk, const float* __restrict__ kw1,
    float* __restrict__ svg)
{
    const int t = blockIdx.x * 256 + threadIdx.x;
    const float t0 = tk[(size_t)t * 2], t1 = tk[(size_t)t * 2 + 1];
    float* op = svg + (size_t)t * 16;
    #pragma unroll
    for (int cc = 0; cc < 4; ++cc) {
        float4 v;
        v.x = fmaf(t0, kw1[cc * 4 + 0], t1 * kw1[16 + cc * 4 + 0]);
        v.y = fmaf(t0, kw1[cc * 4 + 1], t1 * kw1[16 + cc * 4 + 1]);
        v.z = fmaf(t0, kw1[cc * 4 + 2], t1 * kw1[16 + cc * 4 + 2]);
        v.w = fmaf(t0, kw1[cc * 4 + 3], t1 * kw1[16 + cc * 4 + 3]);
        *(float4*)(op + cc * 4) = v;
    }
}

// ===========================================================================
// wconv: Wt[n][k] bf16 = W[k][n] f32. 512x512, 4 matrices.
// ===========================================================================
__global__ __launch_bounds__(256) void wconv(
    const float* __restrict__ w0, const float* __restrict__ w1,
    const float* __restrict__ w2, const float* __restrict__ w3,
    u16* __restrict__ o0, u16* __restrict__ o1,
    u16* __restrict__ o2, u16* __restrict__ o3)
{
    const float* W[4] = {w0, w1, w2, w3};
    u16*         O[4] = {o0, o1, o2, o3};
    __shared__ float L[64][65];
    const int z = blockIdx.z, tid = threadIdx.x;
    const int k0 = blockIdx.x * 64, n0 = blockIdx.y * 64;
    const float* Wz = W[z];
    #pragma unroll
    for (int i = 0; i < 16; ++i) {
        int idx = tid + i * 256;
        int k = idx >> 6, n = idx & 63;
        L[n][k] = Wz[(size_t)(k0 + k) * 512 + n0 + n];
    }
    __syncthreads();
    u32* Oz = (u32*)O[z];
    #pragma unroll
    for (int i = 0; i < 8; ++i) {
        int idx = tid + i * 256;
        int n = idx >> 5, kp = idx & 31;
        Oz[((size_t)(n0 + n) * 512 + k0 + kp * 2) >> 1] = pk2(L[n][kp * 2], L[n][kp * 2 + 1]);
    }
}

// ===========================================================================
// GEMM: C = A[8192x512](bf16) @ Wt^T (+bias). Rows padded to 36 u16 in LDS
// (bank<=2-way on frag reads; old quad-major layout was 8-way).
// ===========================================================================
struct GArgs {
    const u16* A[3];
    const u16* W[3];
    void*      C[3];
    const float* bias;
    int modeT[3];
    int outf32;
};

__global__ __launch_bounds__(256) void gemm_mfma(GArgs g) {
    __shared__ u16 Xs[128][36];
    __shared__ u16 Ws[128][36];

    const int z   = blockIdx.z;
    const int tid = threadIdx.x;
    const int w = tid >> 6, lane = tid & 63, quad = lane >> 4, l16 = lane & 15;
    const int wm = w >> 1, wn = w & 1;
    const int n0 = blockIdx.x * 128, t0 = blockIdx.y * 128;
    const int trans = g.modeT[z];

    f4 acc[4][4];
    #pragma unroll
    for (int i = 0; i < 4; ++i)
        #pragma unroll
        for (int j = 0; j < 4; ++j) acc[i][j] = (f4)0.f;

    const u16* Ap = g.A[z];
    const u16* Wp = g.W[z];

    for (int kc = 0; kc < 512; kc += 32) {
        __syncthreads();
        #pragma unroll
        for (int i = 0; i < 2; ++i) {
            const int cc = tid + i * 256;
            const int row = cc >> 2, seg = cc & 3;
            *(uint4*)&Xs[row][seg * 8] =
                *(const uint4*)(Ap + (size_t)(t0 + row) * 512 + kc + seg * 8);
            *(uint4*)&Ws[row][seg * 8] =
                *(const uint4*)(Wp + (size_t)(n0 + row) * 512 + kc + seg * 8);
        }
        __syncthreads();

        const u16 (*Aop)[36] = trans ? Xs : Ws;
        const u16 (*Bop)[36] = trans ? Ws : Xs;
        const int arow = (trans ? wm : wn) * 64;
        const int brow = (trans ? wn : wm) * 64;
        bf8 af[4], bf[4];
        #pragma unroll
        for (int i = 0; i < 4; ++i) af[i] = *(const bf8*)&Aop[arow + i * 16 + l16][quad * 8];
        #pragma unroll
        for (int j = 0; j < 4; ++j) bf[j] = *(const bf8*)&Bop[brow + j * 16 + l16][quad * 8];
        #pragma unroll
        for (int i = 0; i < 4; ++i)
            #pragma unroll
            for (int j = 0; j < 4; ++j)
                acc[i][j] = __builtin_amdgcn_mfma_f32_16x16x32_bf16(af[i], bf[j], acc[i][j], 0, 0, 0);
    }

    if (g.outf32) {
        float* Co = (float*)g.C[z];
        #pragma unroll
        for (int i = 0; i < 4; ++i) {
            const int nb = n0 + wn * 64 + i * 16 + quad * 4;
            float4 bv = *(const float4*)&g.bias[nb];
            #pragma unroll
            for (int j = 0; j < 4; ++j) {
                const int tok = t0 + wm * 64 + j * 16 + l16;
                float4 st;
                st.x = acc[i][j][0] + bv.x; st.y = acc[i][j][1] + bv.y;
                st.z = acc[i][j][2] + bv.z; st.w = acc[i][j][3] + bv.w;
                *(float4*)&Co[(size_t)tok * 512 + nb] = st;
            }
        }
    } else if (!trans) {
        u16* C = (u16*)g.C[z];
        #pragma unroll
        for (int i = 0; i < 4; ++i) {
            const int nb = n0 + wn * 64 + i * 16 + quad * 4;
            #pragma unroll
            for (int j = 0; j < 4; ++j) {
                const int tok = t0 + wm * 64 + j * 16 + l16;
                uint2 pw;
                pw.x = pk2(acc[i][j][0], acc[i][j][1]);
                pw.y = pk2(acc[i][j][2], acc[i][j][3]);
                *(uint2*)&C[(size_t)tok * 512 + nb] = pw;
            }
        }
    } else {
        u16* Vt = (u16*)g.C[z];
        #pragma unroll
        for (int i = 0; i < 4; ++i) {
            const int tokb = t0 + wm * 64 + i * 16 + quad * 4;
            const int mb = tokb >> 10, tb = tokb & 1023;
            #pragma unroll
            for (int j = 0; j < 4; ++j) {
                const int n = n0 + wn * 64 + j * 16 + l16;
                uint2 pw;
                pw.x = pk2(acc[i][j][0], acc[i][j][1]);
                pw.y = pk2(acc[i][j][2], acc[i][j][3]);
                *(uint2*)&Vt[(size_t)mb * 524288 + (size_t)n * 1024 + tb] = pw;
            }
        }
    }
}

// ===========================================================================
// Fused attention v5: block = (m, 32-q tile, head-group of 4). 256 threads =
// 4 waves; wave = head hg*4+w. Grid 8*32*2 = 512 blocks -> 2-3 blocks/CU.
// Bias MLP: one 32x32x16 MFMA per key-row covers all 32 q x 4 h (K=16=KHID,
// no padding). sB[h][k][q] bf16, strides 1156/36 -> <=2-way banks.
// ===========================================================================
__global__ __launch_bounds__(256, 3) void attn_mfma(
    const u16* __restrict__ Q, const u16* __restrict__ K,
    const u16* __restrict__ Vt,
    const float* __restrict__ tqp, const float* __restrict__ svg,
    const float* __restrict__ kw1, const float* __restrict__ kb1,
    const float* __restrict__ kw2,
    u16* __restrict__ O)
{
    __shared__ u16   sB[4 * 1156];     // [h4][k32 * 36 + q32] bf16
    __shared__ u16   sP[4][16][36];    // per-wave P [q][k]
    __shared__ float sv[32][18];       // [k][c16], staged from svg

    const int tid = threadIdx.x;
    const int w = tid >> 6, lane = tid & 63;
    const int quad = lane >> 4, l16 = lane & 15;
    const int l32 = lane & 31, hw = lane >> 5;
    const int m = blockIdx.x;          // XCD ~ m (K/V L2 locality)
    const int q0 = blockIdx.y * 32;
    const int hg = blockIdx.z;
    const int h = hg * 4 + w;

    // ---- loop-invariant setup ----
    bf8 qf[2][2];
    #pragma unroll
    for (int qs = 0; qs < 2; ++qs)
        #pragma unroll
        for (int kc = 0; kc < 2; ++kc)
            qf[qs][kc] = *(const bf8*)(Q + ((size_t)m * 1024 + q0 + qs * 16 + l16) * 512
                                         + h * 64 + kc * 32 + quad * 8);
    // u8[j]: c = hw*8+j, q = q0 + l32
    float u8[8];
    {
        const size_t qi = ((size_t)m * 1024 + q0 + l32) * 2;
        const float t0v = tqp[qi], t1v = tqp[qi + 1];
        #pragma unroll
        for (int j = 0; j < 8; ++j) {
            const int c = hw * 8 + j;
            u8[j] = fmaf(t0v, kw1[c], fmaf(t1v, kw1[16 + c], kb1[c]));
        }
    }
    // b2: B[k=c=hw*8+j][n=l32] = kw2[c][hg*4+l32], zero for l32>=4
    bf8 b2;
    {
        union { uint4 u4; bf8 v; } cv; cv.u4 = make_uint4(0, 0, 0, 0);
        if (l32 < 4) {
            u32 r[4];
            #pragma unroll
            for (int pp = 0; pp < 4; ++pp) {
                const int c = hw * 8 + pp * 2;
                r[pp] = pk2(kw2[c * 8 + hg * 4 + l32], kw2[(c + 1) * 8 + hg * 4 + l32]);
            }
            cv.u4 = make_uint4(r[0], r[1], r[2], r[3]);
        }
        b2 = cv.v;
    }

    float mrun[2] = {-3e38f, -3e38f}, lrun[2] = {0.f, 0.f};
    f4 o[2][4];
    #pragma unroll
    for (int qs = 0; qs < 2; ++qs)
        #pragma unroll
        for (int d = 0; d < 4; ++d) o[qs][d] = (f4)0.f;

    // stage sv(kt=0)
    {
        const int row = tid >> 3, cp = (tid & 7) * 2;
        *(float2*)&sv[row][cp] =
            *(const float2*)(svg + ((size_t)m * 1024 + row) * 16 + cp);
    }
    __syncthreads();

    for (int kt = 0; kt < 32; ++kt) {
        const int k0 = kt * 32;

        // ---- global loads for phase C (latency hidden by phase B) ----
        bf8 kf[2][2], vf[4];
        #pragma unroll
        for (int ms = 0; ms < 2; ++ms)
            #pragma unroll
            for (int kc = 0; kc < 2; ++kc)
                kf[ms][kc] = *(const bf8*)(K + ((size_t)m * 1024 + k0 + ms * 16 + l16) * 512
                                             + h * 64 + kc * 32 + quad * 8);
        #pragma unroll
        for (int ds = 0; ds < 4; ++ds)
            vf[ds] = *(const bf8*)(Vt + (size_t)m * 524288
                                      + (size_t)(h * 64 + ds * 16 + l16) * 1024 + k0 + quad * 8);

        // ---- phase B: bias MFMA, key-rows kr = w*8+tl ----
        #pragma unroll
        for (int tl = 0; tl < 8; ++tl) {
            const int kr = w * 8 + tl;
            float4 v0 = *(const float4*)&sv[kr][hw * 8];
            float4 v1 = *(const float4*)&sv[kr][hw * 8 + 4];
            union { uint4 u4; bf8 v; } cv;
            cv.u4.x = pk2(fmaxf(u8[0] - v0.x, 0.f), fmaxf(u8[1] - v0.y, 0.f));
            cv.u4.y = pk2(fmaxf(u8[2] - v0.z, 0.f), fmaxf(u8[3] - v0.w, 0.f));
            cv.u4.z = pk2(fmaxf(u8[4] - v1.x, 0.f), fmaxf(u8[5] - v1.y, 0.f));
            cv.u4.w = pk2(fmaxf(u8[6] - v1.z, 0.f), fmaxf(u8[7] - v1.w, 0.f));
            f16v d = __builtin_amdgcn_mfma_f32_32x32x16_bf16(cv.v, b2, (f16v)0.f, 0, 0, 0);
            // D: col(l32)=h (l32<4 valid), row = (reg&3) + 8*(reg>>2) + 4*hw = q
            if (l32 < 4) {
                u16* bp = &sB[l32 * 1156 + kr * 36 + hw * 4];
                #pragma unroll
                for (int rg = 0; rg < 4; ++rg) {
                    uint2 pw;
                    pw.x = pk2(d[rg * 4 + 0], d[rg * 4 + 1]);
                    pw.y = pk2(d[rg * 4 + 2], d[rg * 4 + 3]);
                    *(uint2*)&bp[rg * 8] = pw;
                }
            }
        }
        __syncthreads();   // sB ready

        // ---- phase C: S^T, softmax, P·V (wave = its head) ----
        #pragma unroll
        for (int qs = 0; qs < 2; ++qs) {
            f4 s[2];
            #pragma unroll
            for (int ms = 0; ms < 2; ++ms) {
                s[ms] = __builtin_amdgcn_mfma_f32_16x16x32_bf16(kf[ms][0], qf[qs][0], (f4)0.f, 0, 0, 0);
                s[ms] = __builtin_amdgcn_mfma_f32_16x16x32_bf16(kf[ms][1], qf[qs][1], s[ms], 0, 0, 0);
            }
            #pragma unroll
            for (int ms = 0; ms < 2; ++ms)
                #pragma unroll
                for (int r = 0; r < 4; ++r) {
                    const int kl = ms * 16 + quad * 4 + r;
                    s[ms][r] = fmaf(s[ms][r], SCALE,
                                    b2f(sB[w * 1156 + kl * 36 + qs * 16 + l16]));
                }
            float mx = fmaxf(fmaxf(fmaxf(s[0][0], s[0][1]), fmaxf(s[0][2], s[0][3])),
                             fmaxf(fmaxf(s[1][0], s[1][1]), fmaxf(s[1][2], s[1][3])));
            mx = fmaxf(mx, __shfl_xor(mx, 16));
            mx = fmaxf(mx, __shfl_xor(mx, 32));
            const float mnew = fmaxf(mrun[qs], mx);
            const float alpha = __expf(mrun[qs] - mnew);
            float ps = 0.f;
            #pragma unroll
            for (int ms = 0; ms < 2; ++ms)
                #pragma unroll
                for (int r = 0; r < 4; ++r) {
                    float pv = __expf(s[ms][r] - mnew);
                    s[ms][r] = pv;
                    ps += pv;
                }
            ps += __shfl_xor(ps, 16);
            ps += __shfl_xor(ps, 32);
            lrun[qs] = lrun[qs] * alpha + ps;
            mrun[qs] = mnew;
            #pragma unroll
            for (int ds = 0; ds < 4; ++ds) o[qs][ds] = o[qs][ds] * alpha;

            #pragma unroll
            for (int ms = 0; ms < 2; ++ms) {
                uint2 pw;
                pw.x = pk2(s[ms][0], s[ms][1]);
                pw.y = pk2(s[ms][2], s[ms][3]);
                *(uint2*)&sP[w][l16][ms * 16 + quad * 4] = pw;
            }
            bf8 pf = *(const bf8*)&sP[w][l16][quad * 8];
            #pragma unroll
            for (int ds = 0; ds < 4; ++ds)
                o[qs][ds] = __builtin_amdgcn_mfma_f32_16x16x32_bf16(vf[ds], pf, o[qs][ds], 0, 0, 0);
        }

        // ---- stage sv(kt+1) in the phase-C shadow ----
        if (kt < 31) {
            const int row = tid >> 3, cp = (tid & 7) * 2;
            *(float2*)&sv[row][cp] =
                *(const float2*)(svg + ((size_t)m * 1024 + k0 + 32 + row) * 16 + cp);
        }
        __syncthreads();   // sv ready + sB reads done
    }

    // ---- epilogue ----
    #pragma unroll
    for (int qs = 0; qs < 2; ++qs) {
        const float inv = 1.f / lrun[qs];
        u16* og = O + ((size_t)m * 1024 + q0 + qs * 16 + l16) * 512 + h * 64;
        #pragma unroll
        for (int ds = 0; ds < 4; ++ds) {
            uint2 pw;
            pw.x = pk2(o[qs][ds][0] * inv, o[qs][ds][1] * inv);
            pw.y = pk2(o[qs][ds][2] * inv, o[qs][ds][3] * inv);
            *(uint2*)(og + ds * 16 + quad * 4) = pw;
        }
    }
}

// ===========================================================================
extern "C" void kernel_launch(void* const* d_in, const int* in_sizes, int n_in,
                              void* d_out, int out_size, void* d_ws, size_t ws_size,
                              hipStream_t stream) {
    const float* xq    = (const float*)d_in[0];
    const float* xk    = (const float*)d_in[1];
    const float* xv    = (const float*)d_in[2];
    const float* tq    = (const float*)d_in[3];
    const float* tk    = (const float*)d_in[4];
    const float* w_q   = (const float*)d_in[5];
    const float* w_k   = (const float*)d_in[6];
    const float* w_v   = (const float*)d_in[7];
    const float* w_out = (const float*)d_in[8];
    const float* b_out = (const float*)d_in[9];
    const float* kw1   = (const float*)d_in[10];
    const float* kb1   = (const float*)d_in[11];
    const float* kw2   = (const float*)d_in[12];

    const size_t nTok = (size_t)Mb * 1024 * 512;   // 4,194,304
    u16* Qw  = (u16*)d_ws;
    u16* Kp  = Qw + nTok;
    u16* Vt  = Kp + nTok;
    u16* Ob  = Vt + nTok;
    u16* Wt0 = Ob + nTok;           // w_q^T
    u16* Wt1 = Wt0 + 512 * 512;
    u16* Wt2 = Wt1 + 512 * 512;
    u16* Wt3 = Wt2 + 512 * 512;     // w_out^T
    u16* Xb  = Wt3 + 512 * 512;     // bf16 xq,xk,xv [3][8192][512]
    float* svg = (float*)(Xb + 3 * nTok);   // [8][1024][16]

    xconv<<<6144, 256, 0, stream>>>(xq, xk, xv, Xb);
    wconv<<<dim3(8, 8, 4), 256, 0, stream>>>(w_q, w_k, w_v, w_out, Wt0, Wt1, Wt2, Wt3);
    svpre<<<32, 256, 0, stream>>>(tk, kw1, svg);

    GArgs gq;
    gq.A[0] = Xb; gq.A[1] = Xb + nTok; gq.A[2] = Xb + 2 * nTok;
    gq.W[0] = Wt0; gq.W[1] = Wt1; gq.W[2] = Wt2;
    gq.C[0] = Qw;  gq.C[1] = Kp;  gq.C[2] = Vt;
    gq.bias = nullptr;
    gq.modeT[0] = 0; gq.modeT[1] = 0; gq.modeT[2] = 1;
    gq.outf32 = 0;
    gemm_mfma<<<dim3(4, 64, 3), 256, 0, stream>>>(gq);

    attn_mfma<<<dim3(8, 32, 2), 256, 0, stream>>>(Qw, Kp, Vt, tq, svg,
                                                  kw1, kb1, kw2, Ob);

    GArgs go;
    go.A[0] = Ob;  go.A[1] = Ob;  go.A[2] = Ob;
    go.W[0] = Wt3; go.W[1] = Wt3; go.W[2] = Wt3;
    go.C[0] = d_out; go.C[1] = d_out; go.C[2] = d_out;
    go.bias = b_out;
    go.modeT[0] = 0; go.modeT[1] = 0; go.modeT[2] = 0;
    go.outf32 = 1;
    gemm_mfma<<<dim3(4, 64, 1), 256, 0, stream>>>(go);
}

// Round 8
// 309.496 us; speedup vs baseline: 1.2356x; 1.1716x over previous
//
#include <hip/hip_runtime.h>

// MultiHeadTEAttention: M=8, NQ=NKV=1024, DX=512, H=8, HD=64, KHID=16, DT=2
// f32 in/out; bf16 MFMA compute. All 8 heads share one relu computation per
// block; bias kept f32 in LDS and injected via the QK MFMA C-operand.

typedef unsigned short u16;
typedef unsigned int   u32;
typedef short bf8  __attribute__((ext_vector_type(8)));    // 8 bf16 = 4 VGPR
typedef float f4   __attribute__((ext_vector_type(4)));

#define Mb 8

// round-half-up bf16 pack: 3 VALU (2 adds + v_perm). Exact on bf16-clean f32.
__device__ __forceinline__ u32 pk2fast(float a, float b) {
    u32 ua = __float_as_uint(a) + 0x8000u;
    u32 ub = __float_as_uint(b) + 0x8000u;
    return __builtin_amdgcn_perm(ub, ua, 0x07060302u);
}

// ===========================================================================
// prep: fused xconv (blocks 0..6143) + wconv (6144..6399) + svpre (6400..6431)
// ===========================================================================
__global__ __launch_bounds__(256) void prep(
    const float* __restrict__ xq, const float* __restrict__ xk,
    const float* __restrict__ xv, u16* __restrict__ Xb,
    const float* __restrict__ w0, const float* __restrict__ w1,
    const float* __restrict__ w2, const float* __restrict__ w3,
    u16* __restrict__ o0, u16* __restrict__ o1,
    u16* __restrict__ o2, u16* __restrict__ o3,
    const float* __restrict__ tk, const float* __restrict__ kw1,
    float* __restrict__ svg)
{
    __shared__ float L[64][65];
    const int blk = blockIdx.x, tid = threadIdx.x;
    if (blk < 6144) {
        const size_t n = (size_t)Mb * 1024 * 512;
        size_t i = ((size_t)blk * 256 + tid) * 8;
        const float* src; size_t off;
        if (i < n)          { src = xq; off = i; }
        else if (i < 2 * n) { src = xk; off = i - n; }
        else                { src = xv; off = i - 2 * n; }
        float4 v0 = *(const float4*)(src + off);
        float4 v1 = *(const float4*)(src + off + 4);
        uint4 u;
        u.x = pk2fast(v0.x, v0.y); u.y = pk2fast(v0.z, v0.w);
        u.z = pk2fast(v1.x, v1.y); u.w = pk2fast(v1.z, v1.w);
        *(uint4*)(Xb + i) = u;
    } else if (blk < 6400) {
        const int b = blk - 6144;
        const int z = b & 3, rest = b >> 2;
        const int k0 = (rest >> 3) * 64, n0 = (rest & 7) * 64;
        const float* W = z == 0 ? w0 : z == 1 ? w1 : z == 2 ? w2 : w3;
        u16*         O = z == 0 ? o0 : z == 1 ? o1 : z == 2 ? o2 : o3;
        #pragma unroll
        for (int i = 0; i < 16; ++i) {
            int idx = tid + i * 256;
            int k = idx >> 6, nn = idx & 63;
            L[nn][k] = W[(size_t)(k0 + k) * 512 + n0 + nn];
        }
        __syncthreads();
        u32* Oz = (u32*)O;
        #pragma unroll
        for (int i = 0; i < 8; ++i) {
            int idx = tid + i * 256;
            int nn = idx >> 5, kp = idx & 31;
            Oz[((size_t)(n0 + nn) * 512 + k0 + kp * 2) >> 1] =
                pk2fast(L[nn][kp * 2], L[nn][kp * 2 + 1]);
        }
    } else {
        const int t = (blk - 6400) * 256 + tid;
        const float t0 = tk[(size_t)t * 2], t1 = tk[(size_t)t * 2 + 1];
        float* op = svg + (size_t)t * 16;
        #pragma unroll
        for (int cc = 0; cc < 4; ++cc) {
            float4 v;
            v.x = fmaf(t0, kw1[cc * 4 + 0], t1 * kw1[16 + cc * 4 + 0]);
            v.y = fmaf(t0, kw1[cc * 4 + 1], t1 * kw1[16 + cc * 4 + 1]);
            v.z = fmaf(t0, kw1[cc * 4 + 2], t1 * kw1[16 + cc * 4 + 2]);
            v.w = fmaf(t0, kw1[cc * 4 + 3], t1 * kw1[16 + cc * 4 + 3]);
            *(float4*)(op + cc * 4) = v;
        }
    }
}

// ===========================================================================
// GEMM: C = A[8192x512](bf16) @ Wt^T (+bias). r6-measured LDS layout.
// oscale folds attention SCALE (2^-3, exact) into the Q projection.
// ===========================================================================
struct GArgs {
    const u16* A[3];
    const u16* W[3];
    void*      C[3];
    const float* bias;
    float oscale[3];
    int modeT[3];
    int outf32;
};

__global__ __launch_bounds__(256) void gemm_mfma(GArgs g) {
    __shared__ u16 Xs[4][128][8];
    __shared__ u16 Ws[4][128][8];

    const int z   = blockIdx.z;
    const int tid = threadIdx.x;
    const int w = tid >> 6, lane = tid & 63, quad = lane >> 4, l16 = lane & 15;
    const int wm = w >> 1, wn = w & 1;
    const int n0 = blockIdx.x * 128, t0 = blockIdx.y * 128;
    const int trans = g.modeT[z];

    f4 acc[4][4];
    #pragma unroll
    for (int i = 0; i < 4; ++i)
        #pragma unroll
        for (int j = 0; j < 4; ++j) acc[i][j] = (f4)0.f;

    const u16* Ap = g.A[z];
    const u16* Wp = g.W[z];

    for (int kc = 0; kc < 512; kc += 32) {
        __syncthreads();
        #pragma unroll
        for (int i = 0; i < 2; ++i) {
            const int cc = tid + i * 256;
            const int row = cc >> 2, seg = cc & 3;
            *(uint4*)&Xs[seg][row][0] =
                *(const uint4*)(Ap + (size_t)(t0 + row) * 512 + kc + seg * 8);
            *(uint4*)&Ws[seg][row][0] =
                *(const uint4*)(Wp + (size_t)(n0 + row) * 512 + kc + seg * 8);
        }
        __syncthreads();

        const u16 (*Aop)[128][8] = trans ? Xs : Ws;
        const u16 (*Bop)[128][8] = trans ? Ws : Xs;
        const int arow = (trans ? wm : wn) * 64;
        const int brow = (trans ? wn : wm) * 64;
        bf8 af[4], bf[4];
        #pragma unroll
        for (int i = 0; i < 4; ++i) af[i] = *(const bf8*)&Aop[quad][arow + i * 16 + l16][0];
        #pragma unroll
        for (int j = 0; j < 4; ++j) bf[j] = *(const bf8*)&Bop[quad][brow + j * 16 + l16][0];
        #pragma unroll
        for (int i = 0; i < 4; ++i)
            #pragma unroll
            for (int j = 0; j < 4; ++j)
                acc[i][j] = __builtin_amdgcn_mfma_f32_16x16x32_bf16(af[i], bf[j], acc[i][j], 0, 0, 0);
    }

    const float sc = g.oscale[z];
    if (g.outf32) {
        float* Co = (float*)g.C[z];
        #pragma unroll
        for (int i = 0; i < 4; ++i) {
            const int nb = n0 + wn * 64 + i * 16 + quad * 4;
            float4 bv = *(const float4*)&g.bias[nb];
            #pragma unroll
            for (int j = 0; j < 4; ++j) {
                const int tok = t0 + wm * 64 + j * 16 + l16;
                float4 st;
                st.x = acc[i][j][0] + bv.x; st.y = acc[i][j][1] + bv.y;
                st.z = acc[i][j][2] + bv.z; st.w = acc[i][j][3] + bv.w;
                *(float4*)&Co[(size_t)tok * 512 + nb] = st;
            }
        }
    } else if (!trans) {
        u16* C = (u16*)g.C[z];
        #pragma unroll
        for (int i = 0; i < 4; ++i) {
            const int nb = n0 + wn * 64 + i * 16 + quad * 4;
            #pragma unroll
            for (int j = 0; j < 4; ++j) {
                const int tok = t0 + wm * 64 + j * 16 + l16;
                uint2 pw;
                pw.x = pk2fast(acc[i][j][0] * sc, acc[i][j][1] * sc);
                pw.y = pk2fast(acc[i][j][2] * sc, acc[i][j][3] * sc);
                *(uint2*)&C[(size_t)tok * 512 + nb] = pw;
            }
        }
    } else {
        u16* Vt = (u16*)g.C[z];
        #pragma unroll
        for (int i = 0; i < 4; ++i) {
            const int tokb = t0 + wm * 64 + i * 16 + quad * 4;
            const int mb = tokb >> 10, tb = tokb & 1023;
            #pragma unroll
            for (int j = 0; j < 4; ++j) {
                const int n = n0 + wn * 64 + j * 16 + l16;
                uint2 pw;
                pw.x = pk2fast(acc[i][j][0], acc[i][j][1]);
                pw.y = pk2fast(acc[i][j][2], acc[i][j][3]);
                *(uint2*)&Vt[(size_t)mb * 524288 + (size_t)n * 1024 + tb] = pw;
            }
        }
    }
}

// ===========================================================================
// Fused attention v6: block = (m, 16-q tile), 256 thr = 4 waves; each wave
// owns heads {w, w+4} -> all 8 heads per block, relu shared. Bias MFMA packs
// TWO key-rows per 16x16x32 (block-diag kw2), output kept f32 in sB and fed
// to the QK MFMA as C-operand (SCALE pre-folded into Q).
// ===========================================================================
__global__ __launch_bounds__(256, 2) void attn_mfma(
    const u16* __restrict__ Q, const u16* __restrict__ K,
    const u16* __restrict__ Vt,
    const float* __restrict__ tqp, const float* __restrict__ svg,
    const float* __restrict__ kw1, const float* __restrict__ kb1,
    const float* __restrict__ kw2,
    u16* __restrict__ O)
{
    __shared__ float sB[32 * 145];     // [k][q*9 + h] f32
    __shared__ u16   sP[4][16][36];    // per-wave P [q][k]
    __shared__ float sv[32][18];       // [k][c16]

    const int tid = threadIdx.x;
    const int w = tid >> 6, lane = tid & 63, quad = lane >> 4, l16 = lane & 15;
    const int m = blockIdx.x;          // XCD ~ m (K/V L2 locality)
    const int q0 = blockIdx.y * 16;

    // ---- loop-invariant setup ----
    bf8 qf[2][2];
    #pragma unroll
    for (int hd = 0; hd < 2; ++hd)
        #pragma unroll
        for (int kc = 0; kc < 2; ++kc)
            qf[hd][kc] = *(const bf8*)(Q + ((size_t)m * 1024 + q0 + l16) * 512
                                         + (w + hd * 4) * 64 + kc * 32 + quad * 8);
    // u8[j]: q = q0+l16, c = (quad&1)*8+j
    float u8[8];
    {
        const size_t qi = ((size_t)m * 1024 + q0 + l16) * 2;
        const float t0v = tqp[qi], t1v = tqp[qi + 1];
        #pragma unroll
        for (int j = 0; j < 8; ++j) {
            const int c = (quad & 1) * 8 + j;
            u8[j] = fmaf(t0v, kw1[c], fmaf(t1v, kw1[16 + c], kb1[c]));
        }
    }
    // b2: B[k=quad*8+j][n=l16]. k<16 -> cols 0-7 (kr0), k>=16 -> cols 8-15 (kr1)
    bf8 b2;
    {
        union { uint4 u4; bf8 v; } cv; cv.u4 = make_uint4(0, 0, 0, 0);
        if ((quad < 2) == (l16 < 8)) {
            const int h_ = l16 & 7;
            u32 rr[4];
            #pragma unroll
            for (int pp = 0; pp < 4; ++pp) {
                const int c = (quad & 1) * 8 + pp * 2;
                rr[pp] = pk2fast(kw2[c * 8 + h_], kw2[(c + 1) * 8 + h_]);
            }
            cv.u4 = make_uint4(rr[0], rr[1], rr[2], rr[3]);
        }
        b2 = cv.v;
    }

    float mrun[2] = {-3e38f, -3e38f}, lrun[2] = {0.f, 0.f};
    f4 o[2][4];
    #pragma unroll
    for (int hd = 0; hd < 2; ++hd)
        #pragma unroll
        for (int d = 0; d < 4; ++d) o[hd][d] = (f4)0.f;

    // stage sv(kt=0)
    {
        const int row = tid >> 3, cp = (tid & 7) * 2;
        *(float2*)&sv[row][cp] =
            *(const float2*)(svg + ((size_t)m * 1024 + row) * 16 + cp);
    }
    __syncthreads();

    for (int kt = 0; kt < 32; ++kt) {
        const int k0 = kt * 32;

        // ---- global K/V frags for both heads (latency hidden by phase B) ----
        bf8 kf[2][2][2], vf[2][4];
        #pragma unroll
        for (int hd = 0; hd < 2; ++hd) {
            const int h = w + hd * 4;
            #pragma unroll
            for (int ms = 0; ms < 2; ++ms)
                #pragma unroll
                for (int kc = 0; kc < 2; ++kc)
                    kf[hd][ms][kc] = *(const bf8*)(K + ((size_t)m * 1024 + k0 + ms * 16 + l16) * 512
                                                     + h * 64 + kc * 32 + quad * 8);
            #pragma unroll
            for (int ds = 0; ds < 4; ++ds)
                vf[hd][ds] = *(const bf8*)(Vt + (size_t)m * 524288
                                              + (size_t)(h * 64 + ds * 16 + l16) * 1024 + k0 + quad * 8);
        }

        // ---- phase B: bias MFMA, 2 key-rows per MFMA, 4 MFMAs = 8 keys/wave ----
        #pragma unroll
        for (int tl = 0; tl < 4; ++tl) {
            const int kb = w * 8 + tl * 2;
            const int kr = kb + (quad >> 1);
            const float* vp = &sv[kr][(quad & 1) * 8];
            float4 v0 = *(const float4*)vp;
            float4 v1 = *(const float4*)(vp + 4);
            union { uint4 u4; bf8 v; } cv;
            cv.u4.x = pk2fast(fmaxf(u8[0] - v0.x, 0.f), fmaxf(u8[1] - v0.y, 0.f));
            cv.u4.y = pk2fast(fmaxf(u8[2] - v0.z, 0.f), fmaxf(u8[3] - v0.w, 0.f));
            cv.u4.z = pk2fast(fmaxf(u8[4] - v1.x, 0.f), fmaxf(u8[5] - v1.y, 0.f));
            cv.u4.w = pk2fast(fmaxf(u8[6] - v1.z, 0.f), fmaxf(u8[7] - v1.w, 0.f));
            f4 d = __builtin_amdgcn_mfma_f32_16x16x32_bf16(cv.v, b2, (f4)0.f, 0, 0, 0);
            // D: row = quad*4+r = q, col = l16 -> kr = kb+(l16>>3), h = l16&7
            float* bp = &sB[(kb + (l16 >> 3)) * 145 + quad * 4 * 9 + (l16 & 7)];
            #pragma unroll
            for (int r = 0; r < 4; ++r) bp[r * 9] = d[r];
        }
        __syncthreads();   // sB ready

        // ---- phase C: per head: S = K·Q^T + bias(C-op), softmax, P·V ----
        #pragma unroll
        for (int hd = 0; hd < 2; ++hd) {
            const int h = w + hd * 4;
            f4 c0, c1;
            const float* bb = &sB[quad * 4 * 145 + l16 * 9 + h];
            #pragma unroll
            for (int r = 0; r < 4; ++r) c0[r] = bb[r * 145];
            #pragma unroll
            for (int r = 0; r < 4; ++r) c1[r] = bb[(16 + r) * 145];
            f4 s0 = __builtin_amdgcn_mfma_f32_16x16x32_bf16(kf[hd][0][0], qf[hd][0], c0, 0, 0, 0);
            s0     = __builtin_amdgcn_mfma_f32_16x16x32_bf16(kf[hd][0][1], qf[hd][1], s0, 0, 0, 0);
            f4 s1 = __builtin_amdgcn_mfma_f32_16x16x32_bf16(kf[hd][1][0], qf[hd][0], c1, 0, 0, 0);
            s1     = __builtin_amdgcn_mfma_f32_16x16x32_bf16(kf[hd][1][1], qf[hd][1], s1, 0, 0, 0);

            float mx = fmaxf(fmaxf(fmaxf(s0[0], s0[1]), fmaxf(s0[2], s0[3])),
                             fmaxf(fmaxf(s1[0], s1[1]), fmaxf(s1[2], s1[3])));
            mx = fmaxf(mx, __shfl_xor(mx, 16));
            mx = fmaxf(mx, __shfl_xor(mx, 32));
            const float mnew = fmaxf(mrun[hd], mx);
            const float alpha = __expf(mrun[hd] - mnew);
            float ps = 0.f;
            #pragma unroll
            for (int r = 0; r < 4; ++r) {
                s0[r] = __expf(s0[r] - mnew); ps += s0[r];
                s1[r] = __expf(s1[r] - mnew); ps += s1[r];
            }
            ps += __shfl_xor(ps, 16);
            ps += __shfl_xor(ps, 32);
            lrun[hd] = lrun[hd] * alpha + ps;
            mrun[hd] = mnew;
            #pragma unroll
            for (int ds = 0; ds < 4; ++ds) o[hd][ds] = o[hd][ds] * alpha;

            uint2 pw0, pw1;
            pw0.x = pk2fast(s0[0], s0[1]); pw0.y = pk2fast(s0[2], s0[3]);
            pw1.x = pk2fast(s1[0], s1[1]); pw1.y = pk2fast(s1[2], s1[3]);
            *(uint2*)&sP[w][l16][quad * 4]      = pw0;
            *(uint2*)&sP[w][l16][16 + quad * 4] = pw1;
            bf8 pf = *(const bf8*)&sP[w][l16][quad * 8];
            #pragma unroll
            for (int ds = 0; ds < 4; ++ds)
                o[hd][ds] = __builtin_amdgcn_mfma_f32_16x16x32_bf16(vf[hd][ds], pf, o[hd][ds], 0, 0, 0);
        }

        // ---- stage sv(kt+1) in the phase-C shadow ----
        if (kt < 31) {
            const int row = tid >> 3, cp = (tid & 7) * 2;
            *(float2*)&sv[row][cp] =
                *(const float2*)(svg + ((size_t)m * 1024 + k0 + 32 + row) * 16 + cp);
        }
        __syncthreads();   // sv ready + sB reads done
    }

    // ---- epilogue ----
    #pragma unroll
    for (int hd = 0; hd < 2; ++hd) {
        const float inv = 1.f / lrun[hd];
        const int h = w + hd * 4;
        u16* og = O + ((size_t)m * 1024 + q0 + l16) * 512 + h * 64;
        #pragma unroll
        for (int ds = 0; ds < 4; ++ds) {
            uint2 pw;
            pw.x = pk2fast(o[hd][ds][0] * inv, o[hd][ds][1] * inv);
            pw.y = pk2fast(o[hd][ds][2] * inv, o[hd][ds][3] * inv);
            *(uint2*)(og + ds * 16 + quad * 4) = pw;
        }
    }
}

// ===========================================================================
extern "C" void kernel_launch(void* const* d_in, const int* in_sizes, int n_in,
                              void* d_out, int out_size, void* d_ws, size_t ws_size,
                              hipStream_t stream) {
    const float* xq    = (const float*)d_in[0];
    const float* xk    = (const float*)d_in[1];
    const float* xv    = (const float*)d_in[2];
    const float* tq    = (const float*)d_in[3];
    const float* tk    = (const float*)d_in[4];
    const float* w_q   = (const float*)d_in[5];
    const float* w_k   = (const float*)d_in[6];
    const float* w_v   = (const float*)d_in[7];
    const float* w_out = (const float*)d_in[8];
    const float* b_out = (const float*)d_in[9];
    const float* kw1   = (const float*)d_in[10];
    const float* kb1   = (const float*)d_in[11];
    const float* kw2   = (const float*)d_in[12];

    const size_t nTok = (size_t)Mb * 1024 * 512;   // 4,194,304
    u16* Qw  = (u16*)d_ws;
    u16* Kp  = Qw + nTok;
    u16* Vt  = Kp + nTok;
    u16* Ob  = Vt + nTok;
    u16* Wt0 = Ob + nTok;           // w_q^T
    u16* Wt1 = Wt0 + 512 * 512;
    u16* Wt2 = Wt1 + 512 * 512;
    u16* Wt3 = Wt2 + 512 * 512;     // w_out^T
    u16* Xb  = Wt3 + 512 * 512;     // bf16 xq,xk,xv [3][8192][512]
    float* svg = (float*)(Xb + 3 * nTok);   // [8][1024][16]

    prep<<<6432, 256, 0, stream>>>(xq, xk, xv, Xb,
                                   w_q, w_k, w_v, w_out, Wt0, Wt1, Wt2, Wt3,
                                   tk, kw1, svg);

    GArgs gq;
    gq.A[0] = Xb; gq.A[1] = Xb + nTok; gq.A[2] = Xb + 2 * nTok;
    gq.W[0] = Wt0; gq.W[1] = Wt1; gq.W[2] = Wt2;
    gq.C[0] = Qw;  gq.C[1] = Kp;  gq.C[2] = Vt;
    gq.bias = nullptr;
    gq.oscale[0] = 0.125f; gq.oscale[1] = 1.f; gq.oscale[2] = 1.f;
    gq.modeT[0] = 0; gq.modeT[1] = 0; gq.modeT[2] = 1;
    gq.outf32 = 0;
    gemm_mfma<<<dim3(4, 64, 3), 256, 0, stream>>>(gq);

    attn_mfma<<<dim3(8, 64), 256, 0, stream>>>(Qw, Kp, Vt, tq, svg,
                                               kw1, kb1, kw2, Ob);

    GArgs go;
    go.A[0] = Ob;  go.A[1] = Ob;  go.A[2] = Ob;
    go.W[0] = Wt3; go.W[1] = Wt3; go.W[2] = Wt3;
    go.C[0] = d_out; go.C[1] = d_out; go.C[2] = d_out;
    go.bias = b_out;
    go.oscale[0] = 1.f; go.oscale[1] = 1.f; go.oscale[2] = 1.f;
    go.modeT[0] = 0; go.modeT[1] = 0; go.modeT[2] = 0;
    go.outf32 = 1;
    gemm_mfma<<<dim3(4, 64, 1), 256, 0, stream>>>(go);
}